// Round 1
// baseline (7109.747 us; speedup 1.0000x reference)
//
#include <hip/hip_runtime.h>

#define Bv    64
#define Sv    200
#define DKv   32
#define NQ1v  4097
#define NWG   8      // workgroups per batch element
#define TPB   256    // wave 0 = serial master, waves 1-3 = 384 bulk rows
#define NSTEP 199

typedef unsigned long long u64;

__device__ __forceinline__ float fsig(float x) {
  return __builtin_amdgcn_rcpf(1.0f + __builtin_amdgcn_exp2f(x * -1.4426950408889634f));
}
__device__ __forceinline__ float ftanh_(float x) {
  return fmaf(2.0f, fsig(2.0f * x), -1.0f);
}
__device__ __forceinline__ u64 packvt(float v, unsigned tag) {
  return ((u64)tag << 32) | (u64)__float_as_uint(v);
}
// Fresh read: RMW executes at the coherence point, immune to stale L2 lines.
__device__ __forceinline__ u64 fresh_read(u64* p) {
  return __hip_atomic_fetch_add(p, 0ull, __ATOMIC_RELAXED, __HIP_MEMORY_SCOPE_AGENT);
}
__device__ __forceinline__ void fresh_write(u64* p, u64 v) {
  (void)__hip_atomic_exchange(p, v, __ATOMIC_RELAXED, __HIP_MEMORY_SCOPE_AGENT);
}

__global__ void lpkt_init(float* out) {
  int i = threadIdx.x;
  if (i < Bv) out[i * Sv] = 0.0f;
}

__global__ __launch_bounds__(TPB, 2) void lpkt_main(
    const int* __restrict__ e_data, const int* __restrict__ at_data,
    const int* __restrict__ it_data, const float* __restrict__ a_data,
    const float* __restrict__ q_matrix,
    const float* __restrict__ E_e, const float* __restrict__ E_at, const float* __restrict__ E_it,
    const float* __restrict__ W1, const float* __restrict__ b1,
    const float* __restrict__ W2, const float* __restrict__ b2,
    const float* __restrict__ W3, const float* __restrict__ b3,
    const float* __restrict__ W4, const float* __restrict__ b4,
    const float* __restrict__ W5, const float* __restrict__ b5,
    const float* __restrict__ h0, float* __restrict__ out,
    u64* __restrict__ partial)
{
  const int tid = threadIdx.x;
  const int wg  = blockIdx.x & (NWG - 1);
  const int b   = blockIdx.x / NWG;
  const int nbase = wg * 512;
  const bool master = (tid < 64);   // wave 0

  // ---- LDS: weights transposed [f][k] so per-lane-k reads are bank-clean
  __shared__ float W1T[96 * 32];    // W1T[f*32+k] = W1[k][f]
  __shared__ float W2T[128 * 32];
  __shared__ float W3T[128 * 32];
  __shared__ float W4T[96 * 32];    // f<32: W4h (special row); 32..63: W4l; 64..95: W4i
  __shared__ float W5T[64 * 32];
  __shared__ float bL[5 * 32];
  __shared__ __align__(16) float xw[96];      // [ee, ea, a]
  __shared__ __align__(16) float xfull[128];  // [lp, it, lc, ht]
  __shared__ __align__(16) float LG_lds[DKv];
  __shared__ __align__(16) float c_lds[DKv];
  __shared__ __align__(16) float ht_part[DKv];
  __shared__ __align__(16) float h49[DKv];

  // ---- one-time transposed staging
  for (int idx = tid; idx < 32 * 96; idx += TPB) {
    int kk = idx / 96, f = idx - kk * 96;
    W1T[f * 32 + kk] = W1[idx];
    W4T[f * 32 + kk] = W4[idx];
  }
  for (int idx = tid; idx < 32 * 128; idx += TPB) {
    int kk = idx >> 7, f = idx & 127;
    W2T[f * 32 + kk] = W2[idx];
    W3T[f * 32 + kk] = W3[idx];
  }
  for (int idx = tid; idx < 32 * 64; idx += TPB) {
    int kk = idx >> 6, i = idx & 63;
    W5T[i * 32 + kk] = W5[idx];
  }
  if (tid < 32) {
    bL[tid]       = b1[tid]; bL[32 + tid]  = b2[tid]; bL[64 + tid] = b3[tid];
    bL[96 + tid]  = b4[tid]; bL[128 + tid] = b5[tid];
    ht_part[tid] = 0.0f;
  }
  if (wg == 0 && tid < 32) h49[tid] = h0[(size_t)4096 * DKv + tid];

  // ---- row ownership: workers [nbase, nbase+384), master [nbase+384, nbase+512)
  int row0, row1;
  if (master) { row0 = nbase + 384 + tid;      row1 = nbase + 448 + tid; }
  else        { int wt = tid - 64; row0 = nbase + wt; row1 = nbase + 192 + wt; }

  float h[2][DKv];
  {
    const float4* hp0 = (const float4*)(h0 + (size_t)row0 * DKv);
    const float4* hp1 = (const float4*)(h0 + (size_t)row1 * DKv);
#pragma unroll
    for (int i = 0; i < 8; i++) {
      float4 v0 = hp0[i], v1 = hp1[i];
      h[0][4*i]=v0.x; h[0][4*i+1]=v0.y; h[0][4*i+2]=v0.z; h[0][4*i+3]=v0.w;
      h[1][4*i]=v1.x; h[1][4*i+1]=v1.y; h[1][4*i+2]=v1.z; h[1][4*i+3]=v1.w;
    }
  }
  const int e0 = e_data[b * Sv];
  const float* q0 = q_matrix + (size_t)e0 * NQ1v;
  float qcv[2];
  qcv[0] = q0[row0]; qcv[1] = q0[row1];
  float qc49 = (wg == 0) ? q0[4096] : 0.0f;
  __syncthreads();

  // ---- phase 0: h_tilde0 partials; post tag=1
#pragma unroll
  for (int r = 0; r < 2; r++) {
    if (qcv[r] != 0.0f) {
#pragma unroll
      for (int kk = 0; kk < DKv; kk++) atomicAdd(&ht_part[kk], h[r][kk]);
    }
  }
  if (wg == 0 && tid < 32 && qc49 != 0.0f) atomicAdd(&ht_part[tid], h49[tid]);
  __syncthreads();
  if (tid < 32)
    fresh_write(&partial[((size_t)1 * Bv + b) * (NWG * DKv) + wg * DKv + tid],
                packvt(ht_part[tid], 1u));

  float lp_reg = 0.0f;   // learning_pre, element j = tid&31 (master lanes)

  // =================== time loop: 2 barriers/step ===================
  for (int t = 0; t < NSTEP; t++) {
    const unsigned tau_g = (unsigned)(t + 1);
    const unsigned tau_p = (unsigned)(t + 2);
    float acc[2][DKv];
    float qnv[2];
    float qn49 = 0.0f;

    if (master) {
      // ------- serial chain, entirely in wave 0 (overlaps workers' matvec)
      const int j = tid & 31, hf = tid >> 5;
      const int ecur  = e_data[b * Sv + t];
      const int enext = e_data[b * Sv + t + 1];
      const int atc   = at_data[b * Sv + t];
      const int itc   = it_data[b * Sv + t];
      const float av  = a_data[b * Sv + t];
      const float ee  = E_e[(size_t)ecur * DKv + j];
      const float ea  = E_at[(size_t)atc * DKv + j];
      const float ei  = E_it[(size_t)itc * DKv + j];
      const float* qnr = q_matrix + (size_t)enext * NQ1v;
      qnv[0] = qnr[row0]; qnv[1] = qnr[row1];
      if (wg == 0) qn49 = qnr[4096];

      // poll h_tilde partials (tag t+1): lane (j,hf) covers wgs {hf,hf+2,hf+4,hf+6}
      u64* pb = partial + ((size_t)(tau_g % 3) * Bv + b) * (NWG * DKv) + j;
      u64 v[4];
      for (;;) {
        bool ok = true;
#pragma unroll
        for (int c = 0; c < 4; c++) {
          v[c] = fresh_read(&pb[(hf + 2 * c) * DKv]);
          ok = ok && ((unsigned)(v[c] >> 32) == tau_g);
        }
        if (__all(ok)) break;
        __builtin_amdgcn_s_sleep(2);
      }
      float hs = 0.0f;
#pragma unroll
      for (int c = 0; c < 4; c++) hs += __uint_as_float((unsigned)v[c]);
      hs += __shfl_xor(hs, 32);
      const float htv = hs;

      // reset accumulator for THIS step (after our post(t-1), before B_a)
      if (tid < 32) ht_part[tid] = 0.0f;

      // stage x vectors
      if (tid < 32) { xw[tid] = ee; xw[64 + tid] = av;
                      xfull[tid] = lp_reg; xfull[96 + tid] = htv; }
      else          { xw[tid] = ea; xfull[tid] = ei; }

      // lc = b1 + W1·[ee, ea, a]   (half-wave split over f, shfl reduce)
      float s1 = 0.0f;
      {
        const float4* xp = (const float4*)(xw + 48 * hf);
#pragma unroll
        for (int i = 0; i < 12; i++) {
          float4 x4 = xp[i];
          const float* wv = &W1T[(48 * hf + 4 * i) * 32 + j];
          s1 = fmaf(x4.x, wv[0],  s1);
          s1 = fmaf(x4.y, wv[32], s1);
          s1 = fmaf(x4.z, wv[64], s1);
          s1 = fmaf(x4.w, wv[96], s1);
        }
      }
      s1 += __shfl_xor(s1, 32);
      const float lc = s1 + bL[j];
      if (tid < 32) xfull[64 + tid] = lc;

      // lg / gl
      float s2 = 0.0f, s3 = 0.0f;
      {
        const float4* xp = (const float4*)(xfull + 64 * hf);
#pragma unroll
        for (int i = 0; i < 16; i++) {
          float4 x4 = xp[i];
          const int f = (64 * hf + 4 * i) * 32 + j;
          const float* w2 = &W2T[f];
          const float* w3 = &W3T[f];
          s2 = fmaf(x4.x, w2[0],  s2); s3 = fmaf(x4.x, w3[0],  s3);
          s2 = fmaf(x4.y, w2[32], s2); s3 = fmaf(x4.y, w3[32], s3);
          s2 = fmaf(x4.z, w2[64], s2); s3 = fmaf(x4.z, w3[64], s3);
          s2 = fmaf(x4.w, w2[96], s2); s3 = fmaf(x4.w, w3[96], s3);
        }
      }
      s2 += __shfl_xor(s2, 32);
      s3 += __shfl_xor(s3, 32);
      const float LGv = fsig(s3 + bL[64 + j]) * (ftanh_(s2 + bL[32 + j]) + 1.0f) * 0.5f;
      if (tid < 32) LG_lds[tid] = LGv;

      // c = b4 + W4l·LG + W4i·it
      float sc = 0.0f;
      {
        const float4* up = (const float4*)(hf ? (xfull + 32) : LG_lds);
#pragma unroll
        for (int i = 0; i < 8; i++) {
          float4 u4 = up[i];
          const float* wv = &W4T[(32 + 32 * hf + 4 * i) * 32 + j];
          sc = fmaf(u4.x, wv[0],  sc);
          sc = fmaf(u4.y, wv[32], sc);
          sc = fmaf(u4.z, wv[64], sc);
          sc = fmaf(u4.w, wv[96], sc);
        }
      }
      sc += __shfl_xor(sc, 32);
      const float cv = sc + bL[96 + j];
      if (tid < 32) c_lds[tid] = cv;

      // y_{t-1} (wg0 only): z = [E_e[ecur], ht]
      if (wg == 0 && t >= 1) {
        float s5 = 0.0f;
        const float4* zp = (const float4*)(hf ? (xfull + 96) : xw);
#pragma unroll
        for (int i = 0; i < 8; i++) {
          float4 z4 = zp[i];
          const float* wv = &W5T[(32 * hf + 4 * i) * 32 + j];
          s5 = fmaf(z4.x, wv[0],  s5);
          s5 = fmaf(z4.y, wv[32], s5);
          s5 = fmaf(z4.z, wv[64], s5);
          s5 = fmaf(z4.w, wv[96], s5);
        }
        s5 += __shfl_xor(s5, 32);
        float yv = fsig(s5 + bL[128 + j]);
#pragma unroll
        for (int m = 1; m < 32; m <<= 1) yv += __shfl_xor(yv, m);
        if (tid == 0) out[b * Sv + t] = yv * (1.0f / DKv);
      }
      lp_reg = lc;
    } else {
      // ------- workers: prefetch q_next + bulk W4h·h matvec (uniform W4 -> s_load)
      const int enext = e_data[b * Sv + t + 1];
      const float* qnr = q_matrix + (size_t)enext * NQ1v;
      qnv[0] = qnr[row0]; qnv[1] = qnr[row1];
#pragma unroll
      for (int kk = 0; kk < DKv; kk++) {
        float a0 = 0.0f, a1 = 0.0f;
#pragma unroll
        for (int d = 0; d < DKv; d += 4) {
          float4 w = *(const float4*)&W4[kk * 96 + d];
          a0 = fmaf(w.x, h[0][d+0], a0); a1 = fmaf(w.x, h[1][d+0], a1);
          a0 = fmaf(w.y, h[0][d+1], a0); a1 = fmaf(w.y, h[1][d+1], a1);
          a0 = fmaf(w.z, h[0][d+2], a0); a1 = fmaf(w.z, h[1][d+2], a1);
          a0 = fmaf(w.w, h[0][d+3], a0); a1 = fmaf(w.w, h[1][d+3], a1);
        }
        acc[0][kk] = a0; acc[1][kk] = a1;
      }
    }
    __syncthreads();   // B_a : LG/c published, ht_part zeroed

    if (!master) {
      // ------- workers: h update + sparse h_tilde contributions
      float c_r[DKv], lg_r[DKv];
#pragma unroll
      for (int i = 0; i < 8; i++) {
        float4 cc = ((const float4*)c_lds)[i];
        float4 gg = ((const float4*)LG_lds)[i];
        c_r[4*i]=cc.x; c_r[4*i+1]=cc.y; c_r[4*i+2]=cc.z; c_r[4*i+3]=cc.w;
        lg_r[4*i]=gg.x; lg_r[4*i+1]=gg.y; lg_r[4*i+2]=gg.z; lg_r[4*i+3]=gg.w;
      }
#pragma unroll
      for (int r = 0; r < 2; r++) {
        const float qcr = qcv[r];
#pragma unroll
        for (int kk = 0; kk < DKv; kk++) {
          float g = fsig(acc[r][kk] + c_r[kk]);
          h[r][kk] = fmaf(g, h[r][kk], qcr * lg_r[kk]);
        }
        if (qnv[r] != 0.0f) {
#pragma unroll
          for (int kk = 0; kk < DKv; kk++) atomicAdd(&ht_part[kk], h[r][kk]);
        }
        qcv[r] = qnv[r];
      }
    }
    __syncthreads();   // B_b : all worker contributions landed in ht_part

    if (master) {
      // ------- master rows: fused matvec + update (overlaps workers' next matvec)
#pragma unroll
      for (int kk = 0; kk < DKv; kk++) {
        float a0 = 0.0f, a1 = 0.0f;
#pragma unroll
        for (int d = 0; d < DKv; d += 4) {
          float4 w = *(const float4*)&W4[kk * 96 + d];
          a0 = fmaf(w.x, h[0][d+0], a0); a1 = fmaf(w.x, h[1][d+0], a1);
          a0 = fmaf(w.y, h[0][d+1], a0); a1 = fmaf(w.y, h[1][d+1], a1);
          a0 = fmaf(w.z, h[0][d+2], a0); a1 = fmaf(w.z, h[1][d+2], a1);
          a0 = fmaf(w.w, h[0][d+3], a0); a1 = fmaf(w.w, h[1][d+3], a1);
        }
        acc[0][kk] = a0; acc[1][kk] = a1;
      }
      float c_r[DKv], lg_r[DKv];
#pragma unroll
      for (int i = 0; i < 8; i++) {
        float4 cc = ((const float4*)c_lds)[i];
        float4 gg = ((const float4*)LG_lds)[i];
        c_r[4*i]=cc.x; c_r[4*i+1]=cc.y; c_r[4*i+2]=cc.z; c_r[4*i+3]=cc.w;
        lg_r[4*i]=gg.x; lg_r[4*i+1]=gg.y; lg_r[4*i+2]=gg.z; lg_r[4*i+3]=gg.w;
      }
#pragma unroll
      for (int r = 0; r < 2; r++) {
        const float qcr = qcv[r];
#pragma unroll
        for (int kk = 0; kk < DKv; kk++) {
          float g = fsig(acc[r][kk] + c_r[kk]);
          h[r][kk] = fmaf(g, h[r][kk], qcr * lg_r[kk]);
        }
        if (qnv[r] != 0.0f) {
#pragma unroll
          for (int kk = 0; kk < DKv; kk++) atomicAdd(&ht_part[kk], h[r][kk]);
        }
        qcv[r] = qnv[r];
      }
      // special row 4096 (LDS-resident), wg0 lanes 0-31
      if (wg == 0 && tid < 32) {
        float a49 = c_r[tid & 31] * 0.0f + c_lds[tid];
#pragma unroll
        for (int d = 0; d < 32; d += 4) {
          float4 hv = *(const float4*)&h49[d];
          a49 = fmaf(hv.x, W4T[(d+0)*32 + tid], a49);
          a49 = fmaf(hv.y, W4T[(d+1)*32 + tid], a49);
          a49 = fmaf(hv.z, W4T[(d+2)*32 + tid], a49);
          a49 = fmaf(hv.w, W4T[(d+3)*32 + tid], a49);
        }
        float hn = fmaf(fsig(a49), h49[tid], qc49 * LG_lds[tid]);
        h49[tid] = hn;
        if (qn49 != 0.0f) atomicAdd(&ht_part[tid], hn);
      }
      qc49 = qn49;
      // post tagged partial (tag t+2)
      if (tid < 32)
        fresh_write(&partial[((size_t)(tau_p % 3) * Bv + b) * (NWG * DKv) + wg * DKv + tid],
                    packvt(ht_part[tid], tau_p));
    }
  }

  // =================== epilogue: y for pred index 199 (wg0 master only) ===================
  if (wg == 0 && master) {
    const int j = tid & 31, hf = tid >> 5;
    const unsigned tau_f = (unsigned)(NSTEP + 1);   // 200
    u64* pb = partial + ((size_t)(tau_f % 3) * Bv + b) * (NWG * DKv) + j;
    u64 v[4];
    for (;;) {
      bool ok = true;
#pragma unroll
      for (int c = 0; c < 4; c++) {
        v[c] = fresh_read(&pb[(hf + 2 * c) * DKv]);
        ok = ok && ((unsigned)(v[c] >> 32) == tau_f);
      }
      if (__all(ok)) break;
      __builtin_amdgcn_s_sleep(2);
    }
    float hs = 0.0f;
#pragma unroll
    for (int c = 0; c < 4; c++) hs += __uint_as_float((unsigned)v[c]);
    hs += __shfl_xor(hs, 32);
    const int e199 = e_data[b * Sv + 199];
    const float ee = E_e[(size_t)e199 * DKv + j];
    if (tid < 32) { xw[tid] = ee; xfull[96 + tid] = hs; }
    float s5 = 0.0f;
    const float4* zp = (const float4*)(hf ? (xfull + 96) : xw);
#pragma unroll
    for (int i = 0; i < 8; i++) {
      float4 z4 = zp[i];
      const float* wv = &W5T[(32 * hf + 4 * i) * 32 + j];
      s5 = fmaf(z4.x, wv[0],  s5);
      s5 = fmaf(z4.y, wv[32], s5);
      s5 = fmaf(z4.z, wv[64], s5);
      s5 = fmaf(z4.w, wv[96], s5);
    }
    s5 += __shfl_xor(s5, 32);
    float yv = fsig(s5 + bL[128 + j]);
#pragma unroll
    for (int m = 1; m < 32; m <<= 1) yv += __shfl_xor(yv, m);
    if (tid == 0) out[b * Sv + 199] = yv * (1.0f / DKv);
  }
}

extern "C" void kernel_launch(void* const* d_in, const int* in_sizes, int n_in,
                              void* d_out, int out_size, void* d_ws, size_t ws_size,
                              hipStream_t stream) {
  const int*   e_data   = (const int*)d_in[0];
  const int*   at_data  = (const int*)d_in[1];
  const int*   it_data  = (const int*)d_in[2];
  const float* a_data   = (const float*)d_in[3];
  const float* q_matrix = (const float*)d_in[4];
  const float* E_e      = (const float*)d_in[5];
  const float* E_at     = (const float*)d_in[6];
  const float* E_it     = (const float*)d_in[7];
  const float* W1 = (const float*)d_in[8];
  const float* b1 = (const float*)d_in[9];
  const float* W2 = (const float*)d_in[10];
  const float* b2 = (const float*)d_in[11];
  const float* W3 = (const float*)d_in[12];
  const float* b3 = (const float*)d_in[13];
  const float* W4 = (const float*)d_in[14];
  const float* b4 = (const float*)d_in[15];
  const float* W5 = (const float*)d_in[16];
  const float* b5 = (const float*)d_in[17];
  const float* h0 = (const float*)d_in[18];
  float* out = (float*)d_out;

  u64* partial = (u64*)d_ws;   // [3][Bv][NWG][DKv] tagged (tag<<32|value) words

  lpkt_init<<<1, 64, 0, stream>>>(out);
  lpkt_main<<<dim3(Bv * NWG), dim3(TPB), 0, stream>>>(
      e_data, at_data, it_data, a_data, q_matrix, E_e, E_at, E_it,
      W1, b1, W2, b2, W3, b3, W4, b4, W5, b5, h0, out, partial);
}

// Round 2
// 5128.055 us; speedup vs baseline: 1.3864x; 1.3864x over previous
//
#include <hip/hip_runtime.h>

#define Bv    64
#define Sv    200
#define DKv   32
#define NQ1v  4097
#define NWG   8      // workgroups per batch element
#define TPB   512    // threads per workgroup (8 waves)
#define ROWS  1      // rows per thread: 8*512*1 = 4096, +1 special
#define NSTEP 199

typedef unsigned long long u64;

__device__ __forceinline__ float fsig(float x) {
  return __builtin_amdgcn_rcpf(1.0f + __builtin_amdgcn_exp2f(x * -1.4426950408889634f));
}
__device__ __forceinline__ float ftanh_(float x) {
  return fmaf(2.0f, fsig(2.0f * x), -1.0f);
}
__device__ __forceinline__ u64 packvt(float v, unsigned tag) {
  return ((u64)tag << 32) | (u64)__float_as_uint(v);
}
// Fresh read: RMW executes at the coherence point, immune to stale L2 lines.
__device__ __forceinline__ u64 fresh_read(u64* p) {
  return __hip_atomic_fetch_add(p, 0ull, __ATOMIC_RELAXED, __HIP_MEMORY_SCOPE_AGENT);
}
__device__ __forceinline__ void fresh_write(u64* p, u64 v) {
  (void)__hip_atomic_exchange(p, v, __ATOMIC_RELAXED, __HIP_MEMORY_SCOPE_AGENT);
}

__global__ void lpkt_init(float* out) {
  int i = threadIdx.x;
  if (i < Bv) out[i * Sv] = 0.0f;
}

__global__ __launch_bounds__(TPB, 4) void lpkt_main(
    const int* __restrict__ e_data, const int* __restrict__ at_data,
    const int* __restrict__ it_data, const float* __restrict__ a_data,
    const float* __restrict__ q_matrix,
    const float* __restrict__ E_e, const float* __restrict__ E_at, const float* __restrict__ E_it,
    const float* __restrict__ W1, const float* __restrict__ b1,
    const float* __restrict__ W2, const float* __restrict__ b2,
    const float* __restrict__ W3, const float* __restrict__ b3,
    const float* __restrict__ W4, const float* __restrict__ b4,
    const float* __restrict__ W5, const float* __restrict__ b5,
    const float* __restrict__ h0, float* __restrict__ out,
    u64* __restrict__ partial)
{
  const int tid = threadIdx.x;
  const int wg  = blockIdx.x & (NWG - 1);
  const int b   = blockIdx.x / NWG;
  const int k   = tid & 31;
  const int p   = tid >> 5;          // 0..15
  const int nbase = wg * (TPB * ROWS);

  // ---- LDS: all weights resident (strides padded vs 32-bank aliasing)
  __shared__ float W23T[128 * 64];                 // [j][2k]=W2[k][j], [2k+1]=W3[k][j]
  __shared__ __align__(16) float W1L[32 * 100];    // row stride 100 (4-way on b128)
  __shared__ __align__(16) float W4L[32 * 100];
  __shared__ __align__(16) float W5L[32 * 68];
  __shared__ float bL[5 * 32];
  __shared__ __align__(16) float xw_lds[96];
  __shared__ __align__(16) float it_lds[DKv];
  __shared__ __align__(16) float lcA[DKv], lcB[DKv];
  __shared__ __align__(16) float ht_lds[DKv];
  __shared__ __align__(16) float LG_lds[DKv];
  __shared__ __align__(16) float c_lds[DKv];
  __shared__ __align__(16) float red[16][DKv];
  __shared__ __align__(16) float red2[16][DKv];
  __shared__ float ht_part[DKv];
  __shared__ __align__(16) float h49[DKv];

  // ---- one-time staging of weights into LDS
  for (int idx = tid; idx < 128 * 32; idx += TPB) {  // coalesced: j fast
    int j = idx & 127, kk = idx >> 7;
    W23T[j * 64 + 2 * kk]     = W2[kk * 128 + j];
    W23T[j * 64 + 2 * kk + 1] = W3[kk * 128 + j];
  }
  for (int idx = tid; idx < 32 * 96; idx += TPB) {
    int r = idx / 96, c = idx % 96;
    W1L[r * 100 + c] = W1[idx];
    W4L[r * 100 + c] = W4[idx];
  }
  for (int idx = tid; idx < 32 * 64; idx += TPB) {
    int r = idx >> 6, c = idx & 63;
    W5L[r * 68 + c] = W5[idx];
  }
  if (tid < 32) {
    bL[0 * 32 + tid] = b1[tid]; bL[1 * 32 + tid] = b2[tid];
    bL[2 * 32 + tid] = b3[tid]; bL[3 * 32 + tid] = b4[tid];
    bL[4 * 32 + tid] = b5[tid];
  }
  if (tid < DKv) { ht_part[tid] = 0.0f; lcB[tid] = 0.0f; }   // lcB = lp at t=0
  if (wg == 0 && tid < DKv) h49[tid] = h0[4096 * DKv + tid];

  // ---- persistent register state (one row per thread)
  float h[DKv];
  {
    const float4* hp = (const float4*)(h0 + (size_t)(nbase + tid) * DKv);
#pragma unroll
    for (int i = 0; i < 8; i++) {
      float4 v = hp[i];
      h[4*i] = v.x; h[4*i+1] = v.y; h[4*i+2] = v.z; h[4*i+3] = v.w;
    }
  }
  const int e0 = e_data[b * Sv];
  const float* q0 = q_matrix + (size_t)e0 * NQ1v;
  float qc = q0[nbase + tid];
  float qc49 = (wg == 0 && tid < DKv) ? q0[4096] : 0.0f;
  __syncthreads();

  // ---- phase 0: h_tilde0 via sparse LDS atomics; post tag=1
  if (qc != 0.0f) {
#pragma unroll
    for (int kk = 0; kk < DKv; kk++) atomicAdd(&ht_part[kk], h[kk]);
  }
  if (wg == 0 && tid < DKv && qc49 != 0.0f) atomicAdd(&ht_part[tid], h49[tid]);
  __syncthreads();
  if (tid < DKv)
    fresh_write(&partial[((size_t)(1 % 3) * Bv + b) * (NWG * DKv) + wg * DKv + tid],
                packvt(ht_part[tid], 1u));

  // =================== time loop ===================
  for (int t = 0; t < NSTEP; t++) {
    float* lc_cur  = (t & 1) ? lcB : lcA;
    float* lc_prev = (t & 1) ? lcA : lcB;
    const unsigned tau_g = (unsigned)(t + 1);
    const unsigned tau_p = (unsigned)(t + 2);

    // ---- A: prefetch q_next + stage embeddings
    const int ecur  = e_data[b * Sv + t];
    const int enext = e_data[b * Sv + t + 1];
    const int atc   = at_data[b * Sv + t];
    const int itc   = it_data[b * Sv + t];
    const float av  = a_data[b * Sv + t];
    const float* qnr = q_matrix + (size_t)enext * NQ1v;
    float qn = qnr[nbase + tid];
    float qn49 = (wg == 0 && tid < DKv) ? qnr[4096] : 0.0f;

    if (tid < 96)
      xw_lds[tid] = (tid < 32) ? E_e[(size_t)ecur * DKv + tid]
                  : (tid < 64) ? E_at[(size_t)atc * DKv + (tid - 32)] : av;
    else if (tid < 128)
      it_lds[tid - 96] = E_it[(size_t)itc * DKv + (tid - 96)];

    // ---- B: bulk matvec W4h·h (uniform W4 -> s_load; overlaps the sync wait)
    float acc[DKv];
#pragma unroll
    for (int kk = 0; kk < DKv; kk++) {
      float a0 = 0.0f;
#pragma unroll
      for (int d = 0; d < DKv; d += 4) {
        float4 w = *(const float4*)&W4[kk * 96 + d];
        a0 = fmaf(w.x, h[d+0], a0);
        a0 = fmaf(w.y, h[d+1], a0);
        a0 = fmaf(w.z, h[d+2], a0);
        a0 = fmaf(w.w, h[d+3], a0);
      }
      acc[kk] = a0;
    }
    __syncthreads();   // B1

    // ---- S1 (wave-parallel): w0: fresh poll+gather | w2: lc matvec
    if (tid < DKv) {
      u64* pb = partial + ((size_t)(tau_g % 3) * Bv + b) * (NWG * DKv) + tid;
      u64 v[NWG];
      for (;;) {
        bool ok = true;
#pragma unroll
        for (int w2 = 0; w2 < NWG; w2++) {
          v[w2] = fresh_read(&pb[w2 * DKv]);
          ok = ok && ((unsigned)(v[w2] >> 32) == tau_g);
        }
        if (ok) break;
        __builtin_amdgcn_s_sleep(2);
      }
      float s = 0.0f;
#pragma unroll
      for (int w2 = 0; w2 < NWG; w2++) s += __uint_as_float((unsigned)v[w2]);
      ht_lds[tid] = s;
    } else if (tid >= 64 && tid < 96) {
      const int kx = tid - 64;
      float s = bL[0 * 32 + kx];
      const float4* wp = (const float4*)&W1L[kx * 100];
      const float4* xp = (const float4*)xw_lds;
#pragma unroll
      for (int i = 0; i < 24; i++) {
        float4 w = wp[i]; float4 x = xp[i];
        s = fmaf(x.x, w.x, s); s = fmaf(x.y, w.y, s);
        s = fmaf(x.z, w.z, s); s = fmaf(x.w, w.w, s);
      }
      lc_cur[kx] = s;
    }
    __syncthreads();   // B3

    // ---- D: lg/gl split-16 (b64 interleaved W23T: 2-way = free)
    {
      const int seg = p >> 2;                     // 0:lp 1:it 2:lc 3:ht
      const float* sp = (seg == 0) ? lc_prev : (seg == 1) ? it_lds
                      : (seg == 2) ? lc_cur  : ht_lds;
      const int off = (p & 3) * 8;
      float xv[8];
#pragma unroll
      for (int i = 0; i < 2; i++) {
        float4 v = ((const float4*)(sp + off))[i];
        xv[4*i] = v.x; xv[4*i+1] = v.y; xv[4*i+2] = v.z; xv[4*i+3] = v.w;
      }
      float s2 = 0.0f, s3 = 0.0f;
      const int jb = 8 * p;
#pragma unroll
      for (int i = 0; i < 8; i++) {
        float2 w = *(const float2*)&W23T[(jb + i) * 64 + 2 * k];
        s2 = fmaf(xv[i], w.x, s2);
        s3 = fmaf(xv[i], w.y, s3);
      }
      red[p][k] = s2; red2[p][k] = s3;
    }
    __syncthreads();   // B4

    // ---- E: w0: LG | w4: zero ht_part
    if (tid < DKv) {
      float s2 = bL[1 * 32 + tid], s3 = bL[2 * 32 + tid];
#pragma unroll
      for (int pp = 0; pp < 16; pp++) { s2 += red[pp][tid]; s3 += red2[pp][tid]; }
      LG_lds[tid] = fsig(s3) * (ftanh_(s2) + 1.0f) * 0.5f;
    } else if (tid >= 128 && tid < 160) ht_part[tid - 128] = 0.0f;
    __syncthreads();   // B5

    // ---- F: c split-16 (all) | y partials (wg0 waves 2-3, t>=1)
    {
      const float4 u4 = (p < 8) ? *(const float4*)(LG_lds + 4 * p)
                                : *(const float4*)(it_lds + 4 * (p - 8));
      const float4 w = *(const float4*)&W4L[k * 100 + 32 + 4 * p];
      float pc = 0.0f;
      pc = fmaf(u4.x, w.x, pc); pc = fmaf(u4.y, w.y, pc);
      pc = fmaf(u4.z, w.z, pc); pc = fmaf(u4.w, w.w, pc);
      red[p][k] = pc;
    }
    if (wg == 0 && t >= 1 && tid >= 64 && tid < 128) {
      const int p2 = p - 2;
      const float* zs = (p2 == 0) ? xw_lds : ht_lds;   // xw[0:32] = E_e[e_data[t]]
      const float4* wp = (const float4*)&W5L[k * 68 + 32 * p2];
      float acc5 = 0.0f;
#pragma unroll
      for (int i = 0; i < 8; i++) {
        float4 w = wp[i]; float4 z = ((const float4*)zs)[i];
        acc5 = fmaf(z.x, w.x, acc5); acc5 = fmaf(z.y, w.y, acc5);
        acc5 = fmaf(z.z, w.z, acc5); acc5 = fmaf(z.w, w.w, acc5);
      }
      red2[p2][k] = acc5;
    }
    __syncthreads();   // B6

    // ---- G: w0: c sum | wg0 w3: y finish
    if (tid < DKv) {
      float s = bL[3 * 32 + tid];
#pragma unroll
      for (int pp = 0; pp < 16; pp++) s += red[pp][tid];
      c_lds[tid] = s;
    } else if (wg == 0 && t >= 1 && tid >= 96 && tid < 128) {
      const int kx = tid - 96;
      float s = fsig(bL[4 * 32 + kx] + red2[0][kx] + red2[1][kx]);
#pragma unroll
      for (int m = 1; m < 32; m <<= 1) s += __shfl_xor(s, m);
      if (tid == 96) out[b * Sv + t] = s * (1.0f / DKv);
    }
    __syncthreads();   // B7

    // ---- H: update h in place; sparse-atomic h_tilde contributions
    {
      float c_r[DKv], lg_r[DKv];
#pragma unroll
      for (int i = 0; i < 8; i++) {
        float4 cv = ((const float4*)c_lds)[i];
        float4 gv = ((const float4*)LG_lds)[i];
        c_r[4*i] = cv.x; c_r[4*i+1] = cv.y; c_r[4*i+2] = cv.z; c_r[4*i+3] = cv.w;
        lg_r[4*i] = gv.x; lg_r[4*i+1] = gv.y; lg_r[4*i+2] = gv.z; lg_r[4*i+3] = gv.w;
      }
      const float qcr = qc;
#pragma unroll
      for (int kk = 0; kk < DKv; kk++) {
        float g = fsig(acc[kk] + c_r[kk]);
        h[kk] = fmaf(g, h[kk], qcr * lg_r[kk]);
      }
      if (qn != 0.0f) {
#pragma unroll
        for (int kk = 0; kk < DKv; kk++) atomicAdd(&ht_part[kk], h[kk]);
      }
      qc = qn;
    }
    if (wg == 0 && tid < DKv) {      // special row 4096 (LDS-resident)
      float hh[DKv];
#pragma unroll
      for (int i = 0; i < 8; i++) {
        float4 v = ((const float4*)h49)[i];
        hh[4*i] = v.x; hh[4*i+1] = v.y; hh[4*i+2] = v.z; hh[4*i+3] = v.w;
      }
      float a = c_lds[tid];
#pragma unroll
      for (int d = 0; d < DKv; d += 4) {
        float4 w = *(const float4*)&W4L[tid * 100 + d];
        a = fmaf(w.x, hh[d+0], a); a = fmaf(w.y, hh[d+1], a);
        a = fmaf(w.z, hh[d+2], a); a = fmaf(w.w, hh[d+3], a);
      }
      float hn = fmaf(fsig(a), h49[tid], qc49 * LG_lds[tid]);
      h49[tid] = hn;
      if (qn49 != 0.0f) atomicAdd(&ht_part[tid], hn);
      qc49 = qn49;
    }
    __syncthreads();   // B8

    // ---- I: post tagged partial via atomicExch (memory-side, promptly visible)
    if (tid < DKv)
      fresh_write(&partial[((size_t)(tau_p % 3) * Bv + b) * (NWG * DKv) + wg * DKv + tid],
                  packvt(ht_part[tid], tau_p));
  }

  // =================== epilogue: y for pred index 199 (wg0 only) ===================
  if (wg == 0) {
    const unsigned tau_f = (unsigned)(NSTEP + 1);   // 200
    if (tid < DKv) {
      u64* pb = partial + ((size_t)(tau_f % 3) * Bv + b) * (NWG * DKv) + tid;
      u64 v[NWG];
      for (;;) {
        bool ok = true;
#pragma unroll
        for (int w2 = 0; w2 < NWG; w2++) {
          v[w2] = fresh_read(&pb[w2 * DKv]);
          ok = ok && ((unsigned)(v[w2] >> 32) == tau_f);
        }
        if (ok) break;
        __builtin_amdgcn_s_sleep(2);
      }
      float s = 0.0f;
#pragma unroll
      for (int w2 = 0; w2 < NWG; w2++) s += __uint_as_float((unsigned)v[w2]);
      ht_lds[tid] = s;
      xw_lds[tid] = E_e[(size_t)e_data[b * Sv + 199] * DKv + tid];
    }
    __syncthreads();
    if (tid >= 64 && tid < 128) {
      const int p2 = p - 2;
      const float* zs = (p2 == 0) ? xw_lds : ht_lds;
      const float4* wp = (const float4*)&W5L[k * 68 + 32 * p2];
      float acc5 = 0.0f;
#pragma unroll
      for (int i = 0; i < 8; i++) {
        float4 w = wp[i]; float4 z = ((const float4*)zs)[i];
        acc5 = fmaf(z.x, w.x, acc5); acc5 = fmaf(z.y, w.y, acc5);
        acc5 = fmaf(z.z, w.z, acc5); acc5 = fmaf(z.w, w.w, acc5);
      }
      red2[p2][k] = acc5;
    }
    __syncthreads();
    if (tid >= 96 && tid < 128) {
      const int kx = tid - 96;
      float s = fsig(bL[4 * 32 + kx] + red2[0][kx] + red2[1][kx]);
#pragma unroll
      for (int m = 1; m < 32; m <<= 1) s += __shfl_xor(s, m);
      if (tid == 96) out[b * Sv + 199] = s * (1.0f / DKv);
    }
  }
}

extern "C" void kernel_launch(void* const* d_in, const int* in_sizes, int n_in,
                              void* d_out, int out_size, void* d_ws, size_t ws_size,
                              hipStream_t stream) {
  const int*   e_data   = (const int*)d_in[0];
  const int*   at_data  = (const int*)d_in[1];
  const int*   it_data  = (const int*)d_in[2];
  const float* a_data   = (const float*)d_in[3];
  const float* q_matrix = (const float*)d_in[4];
  const float* E_e      = (const float*)d_in[5];
  const float* E_at     = (const float*)d_in[6];
  const float* E_it     = (const float*)d_in[7];
  const float* W1 = (const float*)d_in[8];
  const float* b1 = (const float*)d_in[9];
  const float* W2 = (const float*)d_in[10];
  const float* b2 = (const float*)d_in[11];
  const float* W3 = (const float*)d_in[12];
  const float* b3 = (const float*)d_in[13];
  const float* W4 = (const float*)d_in[14];
  const float* b4 = (const float*)d_in[15];
  const float* W5 = (const float*)d_in[16];
  const float* b5 = (const float*)d_in[17];
  const float* h0 = (const float*)d_in[18];
  float* out = (float*)d_out;

  u64* partial = (u64*)d_ws;   // [3][Bv][NWG][DKv] tagged (tag<<32|value) words

  lpkt_init<<<1, 64, 0, stream>>>(out);
  lpkt_main<<<dim3(Bv * NWG), dim3(TPB), 0, stream>>>(
      e_data, at_data, it_data, a_data, q_matrix, E_e, E_at, E_it,
      W1, b1, W2, b2, W3, b3, W4, b4, W5, b5, h0, out, partial);
}